// Round 4
// baseline (887.580 us; speedup 1.0000x reference)
//
#include <hip/hip_runtime.h>
#include <hip/hip_bf16.h>

typedef __hip_bfloat16 bf16;
typedef unsigned short u16;
typedef short bfrag __attribute__((ext_vector_type(8)));   // 8 bf16 = 4 VGPRs
typedef float f32x4 __attribute__((ext_vector_type(4)));

#define NGRAPH 512
#define BN_EPS 1e-5f

__device__ __forceinline__ float b2f(bf16 x) { return __bfloat162float(x); }
__device__ __forceinline__ float bf_lo(unsigned u) { return __uint_as_float(u << 16); }
__device__ __forceinline__ float bf_hi(unsigned u) { return __uint_as_float(u & 0xffff0000u); }
__device__ __forceinline__ u16 f2u(float v) {
    bf16 t = __float2bfloat16(v);
    u16 r; __builtin_memcpy(&r, &t, 2); return r;
}

// Read element i of a buffer that is either bf16 (isbf16=1) or fp32 (isbf16=0).
__device__ __forceinline__ float load_f(const void* p, int i, int isbf16) {
    if (isbf16) {
        unsigned short u = ((const unsigned short*)p)[i];
        return __uint_as_float(((unsigned int)u) << 16);
    }
    return ((const float*)p)[i];
}

// ---------------- dtype detection (robustness; measured fp32 on this rig) --
__global__ void detect_dtype(const void* __restrict__ x, int* __restrict__ flag) {
    int lane = threadIdx.x & 63;
    unsigned short u = ((const unsigned short*)x)[2 * lane];
    float f = __uint_as_float(((unsigned int)u) << 16);
    int crazy = (!(fabsf(f) <= 1024.0f)) ? 1 : 0;
    unsigned long long m = __ballot(crazy);
    if (threadIdx.x == 0) *flag = (m == 0ULL) ? 1 : 0;   // 1 = bf16, 0 = fp32
}

// ---------------- convert raw input -> bf16 (u16) ----------------
__global__ void cvt_bf(const void* __restrict__ in, u16* __restrict__ out,
                       int n, const int* __restrict__ flag) {
    int i = blockIdx.x * blockDim.x + threadIdx.x;
    if (i < n) out[i] = f2u(load_f(in, i, *flag));
}

// ---------------- repack W[K][N] into MFMA B-fragment order ----------------
// out linear index t = (((kt*(N/16)+nt)*64 + lane)*8 + j)
// holds W[kt*32 + (lane>>4)*8 + j][nt*16 + (lane&15)] as bf16.
__global__ void repack_w(const void* __restrict__ W, u16* __restrict__ out,
                         int Kd, int Nd, const int* __restrict__ flag) {
    int t = blockIdx.x * blockDim.x + threadIdx.x;
    if (t >= Kd * Nd) return;
    int isbf = *flag;
    int j = t & 7;
    int lane = (t >> 3) & 63;
    int tile = t >> 9;
    int NT = Nd / 16;
    int nt = tile % NT, kt = tile / NT;
    int k = kt * 32 + (lane >> 4) * 8 + j;
    int nn = nt * 16 + (lane & 15);
    out[t] = f2u(load_f(W, k * Nd + nn, isbf));
}

__global__ void fold_bn(const void* b, const void* g, const void* be,
                        const void* m, const void* v,
                        float* __restrict__ S, float* __restrict__ T,
                        int F, const int* __restrict__ flag) {
    int f = blockIdx.x * blockDim.x + threadIdx.x;
    if (f >= F) return;
    int isbf = *flag;
    float bb = load_f(b, f, isbf), gg = load_f(g, f, isbf);
    float bee = load_f(be, f, isbf), mm = load_f(m, f, isbf);
    float vv = load_f(v, f, isbf);
    float s = gg * rsqrtf(vv + BN_EPS);
    S[f] = s;
    T[f] = (bb - mm) * s + bee;
}

// ---------------- CSR build (once; reused by all 3 layers) ----------------
__global__ void count_deg_i(const int* __restrict__ dst, int* __restrict__ deg, int e) {
    int i = blockIdx.x * blockDim.x + threadIdx.x;
    if (i < e) atomicAdd(&deg[dst[i]], 1);
}

__global__ void reserve_rows(const int* __restrict__ deg, int* __restrict__ row_start,
                             int* __restrict__ cursor, float* __restrict__ dis,
                             int* __restrict__ total, int n) {
    int i = blockIdx.x * blockDim.x + threadIdx.x;
    if (i >= n) return;
    int d = deg[i];
    int s = atomicAdd(total, d);
    row_start[i] = s;
    cursor[i] = s;
    dis[i] = rsqrtf((float)(d + 1));   // +1 self-loop
}

__global__ void scatter_edges(const int* __restrict__ src, const int* __restrict__ dst,
                              int* __restrict__ cursor, int* __restrict__ csr_src, int e) {
    int i = blockIdx.x * blockDim.x + threadIdx.x;
    if (i >= e) return;
    int pos = atomicAdd(&cursor[dst[i]], 1);
    csr_src[pos] = src[i];
}

// ---------------- MFMA node GEMM: C[M x N] = A[M x K] @ W[K x N] -----------
// A: bf16 row-major [M x K]. Wrep: repacked bf16 fragments. C: bf16 [M x N].
// Block = 256 threads = 4 waves; each block does 64 rows; wave w owns rows
// [w*16, w*16+16). LDS pad: +8 bf16 keeps 16B alignment, <=2-way bank alias.
template <int K, int N>
__global__ __launch_bounds__(256) void mfma_gemm(
    const u16* __restrict__ A, const u16* __restrict__ Wrep,
    u16* __restrict__ C, int M) {
    constexpr int KP = K + 8;
    constexpr int NT = N / 16;
    constexpr int KT = K / 32;
    __shared__ u16 Alds[64 * KP];
    const int m0 = blockIdx.x * 64;
    const int tid = threadIdx.x;
    // stage A tile (rows beyond M read in-workspace pad; stores are guarded)
    for (int c = tid; c < 64 * (K / 8); c += 256) {
        int r = c / (K / 8), kc = c % (K / 8);
        uint4 v = *(const uint4*)(A + (size_t)(m0 + r) * K + kc * 8);
        *(uint4*)(&Alds[r * KP + kc * 8]) = v;
    }
    __syncthreads();
    const int wv = tid >> 6, lane = tid & 63;
    const int mrow = lane & 15;   // row within wave's strip (A), col of D
    const int kb = lane >> 4;     // 0..3
    f32x4 acc[NT];
#pragma unroll
    for (int nt = 0; nt < NT; nt++) acc[nt] = (f32x4){0.f, 0.f, 0.f, 0.f};
#pragma unroll
    for (int kt = 0; kt < KT; kt++) {
        bfrag a = *(const bfrag*)(&Alds[(wv * 16 + mrow) * KP + kt * 32 + kb * 8]);
#pragma unroll
        for (int nt = 0; nt < NT; nt++) {
            bfrag b = *(const bfrag*)(Wrep + ((size_t)(kt * NT + nt) * 64 + lane) * 8);
            acc[nt] = __builtin_amdgcn_mfma_f32_16x16x32_bf16(a, b, acc[nt], 0, 0, 0);
        }
    }
    // epilogue: D row = kb*4 + r, col = mrow  [m89-verified layout]
#pragma unroll
    for (int nt = 0; nt < NT; nt++) {
#pragma unroll
        for (int r = 0; r < 4; r++) {
            int row = m0 + wv * 16 + kb * 4 + r;
            if (row < M) C[(size_t)row * N + nt * 16 + mrow] = f2u(acc[nt][r]);
        }
    }
}

// ---------------- CSR aggregation, fused self-loop + BN + ReLU -------------
// One wave per destination node; bf16 in, bf16 out (fp32 accumulate).
template <int VPL>
__global__ __launch_bounds__(256) void csr_agg(
    const int* __restrict__ row_start, const int* __restrict__ deg,
    const float* __restrict__ dis, const int* __restrict__ csr_src,
    const u16* __restrict__ ht,
    const float* __restrict__ S, const float* __restrict__ T,
    u16* __restrict__ out, int n) {
    const int F = VPL * 64;
    int wid = (int)(((size_t)blockIdx.x * blockDim.x + threadIdx.x) >> 6);
    int lane = threadIdx.x & 63;
    if (wid >= n) return;
    int start = row_start[wid];
    int d = deg[wid];
    float disd = dis[wid];
    float dd = disd * disd;

    float acc[VPL];
    {
        const u16* self = ht + (size_t)wid * F + lane * VPL;
        if (VPL == 4) {
            uint2 u = *(const uint2*)self;
            acc[0] = bf_lo(u.x) * dd; acc[1] = bf_hi(u.x) * dd;
            acc[2] = bf_lo(u.y) * dd; acc[3] = bf_hi(u.y) * dd;
        } else {
            unsigned u = *(const unsigned*)self;
            acc[0] = bf_lo(u) * dd; acc[1] = bf_hi(u) * dd;
        }
    }

    for (int base = 0; base < d; base += 64) {
        int e = base + lane;
        int s = 0; float nw = 0.0f;
        if (e < d) { s = csr_src[start + e]; nw = dis[s] * disd; }
        int cnt = min(64, d - base);
        for (int k = 0; k < cnt; k++) {
            int sk = __shfl(s, k);
            float nwk = __shfl(nw, k);
            const u16* hr = ht + (size_t)sk * F + lane * VPL;
            if (VPL == 4) {
                uint2 u = *(const uint2*)hr;
                acc[0] += nwk * bf_lo(u.x); acc[1] += nwk * bf_hi(u.x);
                acc[2] += nwk * bf_lo(u.y); acc[3] += nwk * bf_hi(u.y);
            } else {
                unsigned u = *(const unsigned*)hr;
                acc[0] += nwk * bf_lo(u); acc[1] += nwk * bf_hi(u);
            }
        }
    }

    // fused BN + ReLU, packed bf16 store
    u16 res[VPL];
#pragma unroll
    for (int c = 0; c < VPL; c++) {
        int f = lane * VPL + c;
        res[c] = f2u(fmaxf(acc[c] * S[f] + T[f], 0.0f));
    }
    u16* orow = out + (size_t)wid * F + lane * VPL;
    if (VPL == 4) {
        uint2 o;
        o.x = (unsigned)res[0] | ((unsigned)res[1] << 16);
        o.y = (unsigned)res[2] | ((unsigned)res[3] << 16);
        *(uint2*)orow = o;
    } else {
        *(unsigned*)orow = (unsigned)res[0] | ((unsigned)res[1] << 16);
    }
}

// ---------------- graph pooling (bf16 features, fp32 accum atomics) --------
__global__ void pool_k(const u16* __restrict__ h, const int* __restrict__ batch,
                       float* __restrict__ psum, float* __restrict__ pmax,
                       int* __restrict__ pcnt, int n) {
    int w = (int)(((size_t)blockIdx.x * blockDim.x + threadIdx.x) >> 6);
    int lane = threadIdx.x & 63;
    if (w >= n) return;
    int g = batch[w];
    if (lane == 0) atomicAdd(&pcnt[g], 1);
    uint2 u = *(const uint2*)(h + (size_t)w * 256 + lane * 4);
    float v[4] = {bf_lo(u.x), bf_hi(u.x), bf_lo(u.y), bf_hi(u.y)};
#pragma unroll
    for (int c = 0; c < 4; c++) {
        int f = lane * 4 + c;
        atomicAdd(&psum[g * 256 + f], v[c]);
        atomicMax((int*)&pmax[g * 256 + f], __float_as_int(v[c]));  // v >= 0
    }
}

__global__ void build_z(const float* __restrict__ psum, const float* __restrict__ pmax,
                        const int* __restrict__ pcnt, float* __restrict__ z) {
    int i = blockIdx.x * blockDim.x + threadIdx.x;
    if (i >= NGRAPH * 256) return;
    int g = i >> 8, f = i & 255;
    float c = (float)max(pcnt[g], 1);
    z[g * 512 + f] = psum[i] / c;
    z[g * 512 + 256 + f] = pmax[i];
}

// ---------------- MLP GEMM (block per row) ----------------
template <int K, int NOUT, bool GELU>
__global__ void mlp_gemm(const float* __restrict__ A, const void* __restrict__ W,
                         const void* __restrict__ bias, float* __restrict__ C,
                         const int* __restrict__ flag) {
    __shared__ float a[K];
    int row = blockIdx.x;
    for (int idx = threadIdx.x; idx < K; idx += blockDim.x) a[idx] = A[row * K + idx];
    __syncthreads();
    int col = threadIdx.x;
    if (col < NOUT) {
        int isbf = *flag;
        float acc = load_f(bias, col, isbf);
        if (isbf) {
            const bf16* w = (const bf16*)W;
            for (int k = 0; k < K; k++) acc += a[k] * b2f(w[k * NOUT + col]);
        } else {
            const float* w = (const float*)W;
            for (int k = 0; k < K; k++) acc += a[k] * w[k * NOUT + col];
        }
        if (GELU) acc = 0.5f * acc * (1.0f + erff(acc * 0.70710678118654752f));
        C[row * NOUT + col] = acc;
    }
}

__global__ void write_out(const float* __restrict__ in, void* __restrict__ out,
                          int n, const int* __restrict__ flag) {
    int i = blockIdx.x * blockDim.x + threadIdx.x;
    if (i >= n) return;
    if (*flag) ((bf16*)out)[i] = __float2bfloat16(in[i]);
    else       ((float*)out)[i] = in[i];
}

extern "C" void kernel_launch(void* const* d_in, const int* in_sizes, int n_in,
                              void* d_out, int out_size, void* d_ws, size_t ws_size,
                              hipStream_t stream) {
    const void* x     = d_in[0];
    const int*  ei    = (const int*)d_in[1];
    const int*  batch = (const int*)d_in[2];
    const void *W1 = d_in[3],  *b1 = d_in[4],  *g1 = d_in[5],  *be1 = d_in[6],  *m1 = d_in[7],  *v1 = d_in[8];
    const void *W2 = d_in[9],  *b2 = d_in[10], *g2 = d_in[11], *be2 = d_in[12], *m2 = d_in[13], *v2 = d_in[14];
    const void *W3 = d_in[15], *b3 = d_in[16], *g3 = d_in[17], *be3 = d_in[18], *m3 = d_in[19], *v3 = d_in[20];
    const void *Wm1 = d_in[21], *bm1 = d_in[22];
    const void *Wm2 = d_in[23], *bm2 = d_in[24];
    const void *Wm3 = d_in[25], *bm3 = d_in[26];

    const int n = in_sizes[0] / 64;     // 50000
    const int E = in_sizes[1] / 2;      // 800000
    const int* src = ei;
    const int* dst = ei + E;
    const int npad = (n + 63 + 64) & ~63;   // padded rows so tile staging stays in-bounds

    // -------- workspace carving (256B aligned), total ~62 MB --------
    size_t off = 0;
    auto carve = [&](size_t bytes) {
        void* p = (char*)d_ws + off;
        off += (bytes + 255) & ~(size_t)255;
        return p;
    };
    int*   flag  = (int*)carve(4);
    int*   total = (int*)carve(4);
    float* dis   = (float*)carve((size_t)n * 4);
    int*   deg_i = (int*)carve((size_t)n * 4);
    int*   rowst = (int*)carve((size_t)n * 4);
    int*   curs  = (int*)carve((size_t)n * 4);
    int*   csrc  = (int*)carve((size_t)E * 4);
    u16*   xbf   = (u16*)carve((size_t)npad * 64 * 2);
    u16*   H     = (u16*)carve((size_t)npad * 256 * 2);   // post-activation h
    u16*   HT    = (u16*)carve((size_t)npad * 256 * 2);   // transformed h_t
    u16*   W1r   = (u16*)carve((size_t)64 * 128 * 2);
    u16*   W2r   = (u16*)carve((size_t)128 * 256 * 2);
    u16*   W3r   = (u16*)carve((size_t)256 * 256 * 2);
    float* S1 = (float*)carve(128 * 4); float* T1 = (float*)carve(128 * 4);
    float* S2 = (float*)carve(256 * 4); float* T2 = (float*)carve(256 * 4);
    float* S3 = (float*)carve(256 * 4); float* T3 = (float*)carve(256 * 4);
    float* psum = (float*)carve((size_t)NGRAPH * 256 * 4);
    float* pmax = (float*)carve((size_t)NGRAPH * 256 * 4);
    int*   pcnt = (int*)carve((size_t)NGRAPH * 4);
    float* z    = (float*)carve((size_t)NGRAPH * 512 * 4);
    float* z1   = (float*)carve((size_t)NGRAPH * 256 * 4);
    float* z2   = (float*)carve((size_t)NGRAPH * 128 * 4);
    float* z3   = (float*)carve((size_t)NGRAPH * 8 * 4);
    (void)ws_size; (void)n_in;

    const int BT = 256;

    // -------- dtype detection + conversions + repacks + BN folding --------
    detect_dtype<<<1, 64, 0, stream>>>(x, flag);
    cvt_bf<<<(n * 64 + BT - 1) / BT, BT, 0, stream>>>(x, xbf, n * 64, flag);
    repack_w<<<(64 * 128 + BT - 1) / BT, BT, 0, stream>>>(W1, W1r, 64, 128, flag);
    repack_w<<<(128 * 256 + BT - 1) / BT, BT, 0, stream>>>(W2, W2r, 128, 256, flag);
    repack_w<<<(256 * 256 + BT - 1) / BT, BT, 0, stream>>>(W3, W3r, 256, 256, flag);
    fold_bn<<<1, 128, 0, stream>>>(b1, g1, be1, m1, v1, S1, T1, 128, flag);
    fold_bn<<<1, 256, 0, stream>>>(b2, g2, be2, m2, v2, S2, T2, 256, flag);
    fold_bn<<<1, 256, 0, stream>>>(b3, g3, be3, m3, v3, S3, T3, 256, flag);

    // -------- CSR build (once) --------
    hipMemsetAsync(deg_i, 0, (size_t)n * 4, stream);
    hipMemsetAsync(total, 0, 4, stream);
    count_deg_i<<<(E + BT - 1) / BT, BT, 0, stream>>>(dst, deg_i, E);
    reserve_rows<<<(n + BT - 1) / BT, BT, 0, stream>>>(deg_i, rowst, curs, dis, total, n);
    scatter_edges<<<(E + BT - 1) / BT, BT, 0, stream>>>(src, dst, curs, csrc, E);

    const int gblocks = (n + 63) / 64;
    const int agg_blocks = (n * 64 + BT - 1) / BT;   // one wave per node

    // -------- layer 1: x(64) -> 128 --------
    mfma_gemm<64, 128><<<gblocks, 256, 0, stream>>>(xbf, W1r, HT, n);
    csr_agg<2><<<agg_blocks, BT, 0, stream>>>(rowst, deg_i, dis, csrc, HT, S1, T1, H, n);

    // -------- layer 2: 128 -> 256 --------
    mfma_gemm<128, 256><<<gblocks, 256, 0, stream>>>(H, W2r, HT, n);
    csr_agg<4><<<agg_blocks, BT, 0, stream>>>(rowst, deg_i, dis, csrc, HT, S2, T2, H, n);

    // -------- layer 3: 256 -> 256 --------
    mfma_gemm<256, 256><<<gblocks, 256, 0, stream>>>(H, W3r, HT, n);
    csr_agg<4><<<agg_blocks, BT, 0, stream>>>(rowst, deg_i, dis, csrc, HT, S3, T3, H, n);

    // -------- pooling --------
    hipMemsetAsync(psum, 0, (size_t)NGRAPH * 256 * 4, stream);
    hipMemsetAsync(pmax, 0, (size_t)NGRAPH * 256 * 4, stream);
    hipMemsetAsync(pcnt, 0, (size_t)NGRAPH * 4, stream);
    pool_k<<<(n * 64 + BT - 1) / BT, BT, 0, stream>>>(H, batch, psum, pmax, pcnt, n);
    build_z<<<(NGRAPH * 256 + BT - 1) / BT, BT, 0, stream>>>(psum, pmax, pcnt, z);

    // -------- MLP head --------
    mlp_gemm<512, 256, true><<<NGRAPH, 256, 0, stream>>>(z, Wm1, bm1, z1, flag);
    mlp_gemm<256, 128, true><<<NGRAPH, 256, 0, stream>>>(z1, Wm2, bm2, z2, flag);
    mlp_gemm<128, 6, false><<<NGRAPH, 128, 0, stream>>>(z2, Wm3, bm3, z3, flag);
    write_out<<<(NGRAPH * 6 + BT - 1) / BT, BT, 0, stream>>>(z3, d_out, NGRAPH * 6, flag);
}

// Round 5
// 553.928 us; speedup vs baseline: 1.6023x; 1.6023x over previous
//
#include <hip/hip_runtime.h>
#include <hip/hip_bf16.h>

typedef __hip_bfloat16 bf16;
typedef unsigned short u16;
typedef short bfrag __attribute__((ext_vector_type(8)));   // 8 bf16 = 4 VGPRs
typedef float f32x4 __attribute__((ext_vector_type(4)));

#define NGRAPH 512
#define BN_EPS 1e-5f

__device__ __forceinline__ float b2f(bf16 x) { return __bfloat162float(x); }
__device__ __forceinline__ float bf_lo(unsigned u) { return __uint_as_float(u << 16); }
__device__ __forceinline__ float bf_hi(unsigned u) { return __uint_as_float(u & 0xffff0000u); }
__device__ __forceinline__ u16 f2u(float v) {
    bf16 t = __float2bfloat16(v);
    u16 r; __builtin_memcpy(&r, &t, 2); return r;
}

// Read element i of a buffer that is either bf16 (isbf16=1) or fp32 (isbf16=0).
__device__ __forceinline__ float load_f(const void* p, int i, int isbf16) {
    if (isbf16) {
        unsigned short u = ((const unsigned short*)p)[i];
        return __uint_as_float(((unsigned int)u) << 16);
    }
    return ((const float*)p)[i];
}

// ---------------- dtype detection (robustness; measured fp32 on this rig) --
__global__ void detect_dtype(const void* __restrict__ x, int* __restrict__ flag) {
    int lane = threadIdx.x & 63;
    unsigned short u = ((const unsigned short*)x)[2 * lane];
    float f = __uint_as_float(((unsigned int)u) << 16);
    int crazy = (!(fabsf(f) <= 1024.0f)) ? 1 : 0;
    unsigned long long m = __ballot(crazy);
    if (threadIdx.x == 0) *flag = (m == 0ULL) ? 1 : 0;   // 1 = bf16, 0 = fp32
}

// ---------------- convert raw input -> bf16 (u16) ----------------
__global__ void cvt_bf(const void* __restrict__ in, u16* __restrict__ out,
                       int n, const int* __restrict__ flag) {
    int i = blockIdx.x * blockDim.x + threadIdx.x;
    if (i < n) out[i] = f2u(load_f(in, i, *flag));
}

// ---------------- repack W[K][N] into MFMA B-fragment order ----------------
// out linear index t = (((kt*(N/16)+nt)*64 + lane)*8 + j)
// holds W[kt*32 + (lane>>4)*8 + j][nt*16 + (lane&15)] as bf16.
__global__ void repack_w(const void* __restrict__ W, u16* __restrict__ out,
                         int Kd, int Nd, const int* __restrict__ flag) {
    int t = blockIdx.x * blockDim.x + threadIdx.x;
    if (t >= Kd * Nd) return;
    int isbf = *flag;
    int j = t & 7;
    int lane = (t >> 3) & 63;
    int tile = t >> 9;
    int NT = Nd / 16;
    int nt = tile % NT, kt = tile / NT;
    int k = kt * 32 + (lane >> 4) * 8 + j;
    int nn = nt * 16 + (lane & 15);
    out[t] = f2u(load_f(W, k * Nd + nn, isbf));
}

__global__ void fold_bn(const void* b, const void* g, const void* be,
                        const void* m, const void* v,
                        float* __restrict__ S, float* __restrict__ T,
                        int F, const int* __restrict__ flag) {
    int f = blockIdx.x * blockDim.x + threadIdx.x;
    if (f >= F) return;
    int isbf = *flag;
    float bb = load_f(b, f, isbf), gg = load_f(g, f, isbf);
    float bee = load_f(be, f, isbf), mm = load_f(m, f, isbf);
    float vv = load_f(v, f, isbf);
    float s = gg * rsqrtf(vv + BN_EPS);
    S[f] = s;
    T[f] = (bb - mm) * s + bee;
}

// ---------------- CSR build (once; reused by all 3 layers) ----------------
__global__ void count_deg_i(const int* __restrict__ dst, int* __restrict__ deg, int e) {
    int i = blockIdx.x * blockDim.x + threadIdx.x;
    if (i < e) atomicAdd(&deg[dst[i]], 1);
}

__global__ void reserve_rows(const int* __restrict__ deg, int* __restrict__ row_start,
                             int* __restrict__ cursor, float* __restrict__ dis,
                             int* __restrict__ total, int n) {
    int i = blockIdx.x * blockDim.x + threadIdx.x;
    if (i >= n) return;
    int d = deg[i];
    int s = atomicAdd(total, d);
    row_start[i] = s;
    cursor[i] = s;
    dis[i] = rsqrtf((float)(d + 1));   // +1 self-loop
}

__global__ void scatter_edges(const int* __restrict__ src, const int* __restrict__ dst,
                              int* __restrict__ cursor, int* __restrict__ csr_src, int e) {
    int i = blockIdx.x * blockDim.x + threadIdx.x;
    if (i >= e) return;
    int pos = atomicAdd(&cursor[dst[i]], 1);
    csr_src[pos] = src[i];
}

// ---------------- MFMA node GEMM: C[M x N] = A[M x K] @ W[K x N] -----------
template <int K, int N>
__global__ __launch_bounds__(256) void mfma_gemm(
    const u16* __restrict__ A, const u16* __restrict__ Wrep,
    u16* __restrict__ C, int M) {
    constexpr int KP = K + 8;
    constexpr int NT = N / 16;
    constexpr int KT = K / 32;
    __shared__ u16 Alds[64 * KP];
    const int m0 = blockIdx.x * 64;
    const int tid = threadIdx.x;
    for (int c = tid; c < 64 * (K / 8); c += 256) {
        int r = c / (K / 8), kc = c % (K / 8);
        uint4 v = *(const uint4*)(A + (size_t)(m0 + r) * K + kc * 8);
        *(uint4*)(&Alds[r * KP + kc * 8]) = v;
    }
    __syncthreads();
    const int wv = tid >> 6, lane = tid & 63;
    const int mrow = lane & 15;
    const int kb = lane >> 4;
    f32x4 acc[NT];
#pragma unroll
    for (int nt = 0; nt < NT; nt++) acc[nt] = (f32x4){0.f, 0.f, 0.f, 0.f};
#pragma unroll
    for (int kt = 0; kt < KT; kt++) {
        bfrag a = *(const bfrag*)(&Alds[(wv * 16 + mrow) * KP + kt * 32 + kb * 8]);
#pragma unroll
        for (int nt = 0; nt < NT; nt++) {
            bfrag b = *(const bfrag*)(Wrep + ((size_t)(kt * NT + nt) * 64 + lane) * 8);
            acc[nt] = __builtin_amdgcn_mfma_f32_16x16x32_bf16(a, b, acc[nt], 0, 0, 0);
        }
    }
#pragma unroll
    for (int nt = 0; nt < NT; nt++) {
#pragma unroll
        for (int r = 0; r < 4; r++) {
            int row = m0 + wv * 16 + kb * 4 + r;
            if (row < M) C[(size_t)row * N + nt * 16 + mrow] = f2u(acc[nt][r]);
        }
    }
}

// ---------------- CSR aggregation, fused self-loop + BN + ReLU -------------
template <int VPL>
__global__ __launch_bounds__(256) void csr_agg(
    const int* __restrict__ row_start, const int* __restrict__ deg,
    const float* __restrict__ dis, const int* __restrict__ csr_src,
    const u16* __restrict__ ht,
    const float* __restrict__ S, const float* __restrict__ T,
    u16* __restrict__ out, int n) {
    const int F = VPL * 64;
    int wid = (int)(((size_t)blockIdx.x * blockDim.x + threadIdx.x) >> 6);
    int lane = threadIdx.x & 63;
    if (wid >= n) return;
    int start = row_start[wid];
    int d = deg[wid];
    float disd = dis[wid];
    float dd = disd * disd;

    float acc[VPL];
    {
        const u16* self = ht + (size_t)wid * F + lane * VPL;
        if (VPL == 4) {
            uint2 u = *(const uint2*)self;
            acc[0] = bf_lo(u.x) * dd; acc[1] = bf_hi(u.x) * dd;
            acc[2] = bf_lo(u.y) * dd; acc[3] = bf_hi(u.y) * dd;
        } else {
            unsigned u = *(const unsigned*)self;
            acc[0] = bf_lo(u) * dd; acc[1] = bf_hi(u) * dd;
        }
    }

    for (int base = 0; base < d; base += 64) {
        int e = base + lane;
        int s = 0; float nw = 0.0f;
        if (e < d) { s = csr_src[start + e]; nw = dis[s] * disd; }
        int cnt = min(64, d - base);
        for (int k = 0; k < cnt; k++) {
            int sk = __shfl(s, k);
            float nwk = __shfl(nw, k);
            const u16* hr = ht + (size_t)sk * F + lane * VPL;
            if (VPL == 4) {
                uint2 u = *(const uint2*)hr;
                acc[0] += nwk * bf_lo(u.x); acc[1] += nwk * bf_hi(u.x);
                acc[2] += nwk * bf_lo(u.y); acc[3] += nwk * bf_hi(u.y);
            } else {
                unsigned u = *(const unsigned*)hr;
                acc[0] += nwk * bf_lo(u); acc[1] += nwk * bf_hi(u);
            }
        }
    }

    u16 res[VPL];
#pragma unroll
    for (int c = 0; c < VPL; c++) {
        int f = lane * VPL + c;
        res[c] = f2u(fmaxf(acc[c] * S[f] + T[f], 0.0f));
    }
    u16* orow = out + (size_t)wid * F + lane * VPL;
    if (VPL == 4) {
        uint2 o;
        o.x = (unsigned)res[0] | ((unsigned)res[1] << 16);
        o.y = (unsigned)res[2] | ((unsigned)res[3] << 16);
        *(uint2*)orow = o;
    } else {
        *(unsigned*)orow = (unsigned)res[0] | ((unsigned)res[1] << 16);
    }
}

// ---------------- segmented pooling over sorted batch ----------------------
// One wave per POOL_NC-node contiguous chunk. Lane owns 4 feature cols
// (uint2 row read = 512B/wave, coalesced). Atomics only at graph boundaries.
#define POOL_NC 64
__global__ __launch_bounds__(256) void pool_seg(
    const u16* __restrict__ h, const int* __restrict__ batch,
    float* __restrict__ psum, float* __restrict__ pmax,
    int* __restrict__ pcnt, int n) {
    int wid = (int)(((size_t)blockIdx.x * blockDim.x + threadIdx.x) >> 6);
    int lane = threadIdx.x & 63;
    int n0 = wid * POOL_NC;
    if (n0 >= n) return;
    int n1 = min(n0 + POOL_NC, n);

    float sum[4] = {0.f, 0.f, 0.f, 0.f};
    float mx[4] = {0.f, 0.f, 0.f, 0.f};
    int cnt = 0;
    int gcur = batch[n0];

    // prefetch first row
    uint2 u_next = *(const uint2*)(h + (size_t)n0 * 256 + lane * 4);
    int g_next = gcur;

    for (int node = n0; node < n1; node++) {
        uint2 u = u_next;
        int g = g_next;
        if (node + 1 < n1) {
            u_next = *(const uint2*)(h + (size_t)(node + 1) * 256 + lane * 4);
            g_next = batch[node + 1];
        }
        if (g != gcur) {
            // flush segment
#pragma unroll
            for (int c = 0; c < 4; c++) {
                atomicAdd(&psum[gcur * 256 + lane * 4 + c], sum[c]);
                atomicMax((int*)&pmax[gcur * 256 + lane * 4 + c], __float_as_int(mx[c]));
                sum[c] = 0.f; mx[c] = 0.f;
            }
            if (lane == 0) atomicAdd(&pcnt[gcur], cnt);
            cnt = 0;
            gcur = g;
        }
        float v0 = bf_lo(u.x), v1 = bf_hi(u.x), v2 = bf_lo(u.y), v3 = bf_hi(u.y);
        sum[0] += v0; sum[1] += v1; sum[2] += v2; sum[3] += v3;
        mx[0] = fmaxf(mx[0], v0); mx[1] = fmaxf(mx[1], v1);
        mx[2] = fmaxf(mx[2], v2); mx[3] = fmaxf(mx[3], v3);
        cnt++;
    }
    // final flush
#pragma unroll
    for (int c = 0; c < 4; c++) {
        atomicAdd(&psum[gcur * 256 + lane * 4 + c], sum[c]);
        atomicMax((int*)&pmax[gcur * 256 + lane * 4 + c], __float_as_int(mx[c]));
    }
    if (lane == 0) atomicAdd(&pcnt[gcur], cnt);
}

__global__ void build_z(const float* __restrict__ psum, const float* __restrict__ pmax,
                        const int* __restrict__ pcnt, float* __restrict__ z) {
    int i = blockIdx.x * blockDim.x + threadIdx.x;
    if (i >= NGRAPH * 256) return;
    int g = i >> 8, f = i & 255;
    float c = (float)max(pcnt[g], 1);
    z[g * 512 + f] = psum[i] / c;
    z[g * 512 + 256 + f] = pmax[i];
}

// ---------------- MLP GEMM (block per row) ----------------
template <int K, int NOUT, bool GELU>
__global__ void mlp_gemm(const float* __restrict__ A, const void* __restrict__ W,
                         const void* __restrict__ bias, float* __restrict__ C,
                         const int* __restrict__ flag) {
    __shared__ float a[K];
    int row = blockIdx.x;
    for (int idx = threadIdx.x; idx < K; idx += blockDim.x) a[idx] = A[row * K + idx];
    __syncthreads();
    int col = threadIdx.x;
    if (col < NOUT) {
        int isbf = *flag;
        float acc = load_f(bias, col, isbf);
        if (isbf) {
            const bf16* w = (const bf16*)W;
            for (int k = 0; k < K; k++) acc += a[k] * b2f(w[k * NOUT + col]);
        } else {
            const float* w = (const float*)W;
            for (int k = 0; k < K; k++) acc += a[k] * w[k * NOUT + col];
        }
        if (GELU) acc = 0.5f * acc * (1.0f + erff(acc * 0.70710678118654752f));
        C[row * NOUT + col] = acc;
    }
}

__global__ void write_out(const float* __restrict__ in, void* __restrict__ out,
                          int n, const int* __restrict__ flag) {
    int i = blockIdx.x * blockDim.x + threadIdx.x;
    if (i >= n) return;
    if (*flag) ((bf16*)out)[i] = __float2bfloat16(in[i]);
    else       ((float*)out)[i] = in[i];
}

extern "C" void kernel_launch(void* const* d_in, const int* in_sizes, int n_in,
                              void* d_out, int out_size, void* d_ws, size_t ws_size,
                              hipStream_t stream) {
    const void* x     = d_in[0];
    const int*  ei    = (const int*)d_in[1];
    const int*  batch = (const int*)d_in[2];
    const void *W1 = d_in[3],  *b1 = d_in[4],  *g1 = d_in[5],  *be1 = d_in[6],  *m1 = d_in[7],  *v1 = d_in[8];
    const void *W2 = d_in[9],  *b2 = d_in[10], *g2 = d_in[11], *be2 = d_in[12], *m2 = d_in[13], *v2 = d_in[14];
    const void *W3 = d_in[15], *b3 = d_in[16], *g3 = d_in[17], *be3 = d_in[18], *m3 = d_in[19], *v3 = d_in[20];
    const void *Wm1 = d_in[21], *bm1 = d_in[22];
    const void *Wm2 = d_in[23], *bm2 = d_in[24];
    const void *Wm3 = d_in[25], *bm3 = d_in[26];

    const int n = in_sizes[0] / 64;     // 50000
    const int E = in_sizes[1] / 2;      // 800000
    const int* src = ei;
    const int* dst = ei + E;
    const int npad = (n + 63 + 64) & ~63;

    size_t off = 0;
    auto carve = [&](size_t bytes) {
        void* p = (char*)d_ws + off;
        off += (bytes + 255) & ~(size_t)255;
        return p;
    };
    int*   flag  = (int*)carve(4);
    int*   total = (int*)carve(4);
    float* dis   = (float*)carve((size_t)n * 4);
    int*   deg_i = (int*)carve((size_t)n * 4);
    int*   rowst = (int*)carve((size_t)n * 4);
    int*   curs  = (int*)carve((size_t)n * 4);
    int*   csrc  = (int*)carve((size_t)E * 4);
    u16*   xbf   = (u16*)carve((size_t)npad * 64 * 2);
    u16*   H     = (u16*)carve((size_t)npad * 256 * 2);
    u16*   HT    = (u16*)carve((size_t)npad * 256 * 2);
    u16*   W1r   = (u16*)carve((size_t)64 * 128 * 2);
    u16*   W2r   = (u16*)carve((size_t)128 * 256 * 2);
    u16*   W3r   = (u16*)carve((size_t)256 * 256 * 2);
    float* S1 = (float*)carve(128 * 4); float* T1 = (float*)carve(128 * 4);
    float* S2 = (float*)carve(256 * 4); float* T2 = (float*)carve(256 * 4);
    float* S3 = (float*)carve(256 * 4); float* T3 = (float*)carve(256 * 4);
    float* psum = (float*)carve((size_t)NGRAPH * 256 * 4);
    float* pmax = (float*)carve((size_t)NGRAPH * 256 * 4);
    int*   pcnt = (int*)carve((size_t)NGRAPH * 4);
    float* z    = (float*)carve((size_t)NGRAPH * 512 * 4);
    float* z1   = (float*)carve((size_t)NGRAPH * 256 * 4);
    float* z2   = (float*)carve((size_t)NGRAPH * 128 * 4);
    float* z3   = (float*)carve((size_t)NGRAPH * 8 * 4);
    (void)ws_size; (void)n_in;

    const int BT = 256;

    detect_dtype<<<1, 64, 0, stream>>>(x, flag);
    cvt_bf<<<(n * 64 + BT - 1) / BT, BT, 0, stream>>>(x, xbf, n * 64, flag);
    repack_w<<<(64 * 128 + BT - 1) / BT, BT, 0, stream>>>(W1, W1r, 64, 128, flag);
    repack_w<<<(128 * 256 + BT - 1) / BT, BT, 0, stream>>>(W2, W2r, 128, 256, flag);
    repack_w<<<(256 * 256 + BT - 1) / BT, BT, 0, stream>>>(W3, W3r, 256, 256, flag);
    fold_bn<<<1, 128, 0, stream>>>(b1, g1, be1, m1, v1, S1, T1, 128, flag);
    fold_bn<<<1, 256, 0, stream>>>(b2, g2, be2, m2, v2, S2, T2, 256, flag);
    fold_bn<<<1, 256, 0, stream>>>(b3, g3, be3, m3, v3, S3, T3, 256, flag);

    hipMemsetAsync(deg_i, 0, (size_t)n * 4, stream);
    hipMemsetAsync(total, 0, 4, stream);
    count_deg_i<<<(E + BT - 1) / BT, BT, 0, stream>>>(dst, deg_i, E);
    reserve_rows<<<(n + BT - 1) / BT, BT, 0, stream>>>(deg_i, rowst, curs, dis, total, n);
    scatter_edges<<<(E + BT - 1) / BT, BT, 0, stream>>>(src, dst, curs, csrc, E);

    const int gblocks = (n + 63) / 64;
    const int agg_blocks = (n * 64 + BT - 1) / BT;

    mfma_gemm<64, 128><<<gblocks, 256, 0, stream>>>(xbf, W1r, HT, n);
    csr_agg<2><<<agg_blocks, BT, 0, stream>>>(rowst, deg_i, dis, csrc, HT, S1, T1, H, n);

    mfma_gemm<128, 256><<<gblocks, 256, 0, stream>>>(H, W2r, HT, n);
    csr_agg<4><<<agg_blocks, BT, 0, stream>>>(rowst, deg_i, dis, csrc, HT, S2, T2, H, n);

    mfma_gemm<256, 256><<<gblocks, 256, 0, stream>>>(H, W3r, HT, n);
    csr_agg<4><<<agg_blocks, BT, 0, stream>>>(rowst, deg_i, dis, csrc, HT, S3, T3, H, n);

    hipMemsetAsync(psum, 0, (size_t)NGRAPH * 256 * 4, stream);
    hipMemsetAsync(pmax, 0, (size_t)NGRAPH * 256 * 4, stream);
    hipMemsetAsync(pcnt, 0, (size_t)NGRAPH * 4, stream);
    const int pool_waves = (n + POOL_NC - 1) / POOL_NC;
    pool_seg<<<(pool_waves * 64 + BT - 1) / BT, BT, 0, stream>>>(H, batch, psum, pmax, pcnt, n);
    build_z<<<(NGRAPH * 256 + BT - 1) / BT, BT, 0, stream>>>(psum, pmax, pcnt, z);

    mlp_gemm<512, 256, true><<<NGRAPH, 256, 0, stream>>>(z, Wm1, bm1, z1, flag);
    mlp_gemm<256, 128, true><<<NGRAPH, 256, 0, stream>>>(z1, Wm2, bm2, z2, flag);
    mlp_gemm<128, 6, false><<<NGRAPH, 128, 0, stream>>>(z2, Wm3, bm3, z3, flag);
    write_out<<<(NGRAPH * 6 + BT - 1) / BT, BT, 0, stream>>>(z3, d_out, NGRAPH * 6, flag);
}

// Round 6
// 497.806 us; speedup vs baseline: 1.7830x; 1.1127x over previous
//
#include <hip/hip_runtime.h>
#include <hip/hip_bf16.h>

typedef __hip_bfloat16 bf16;
typedef unsigned short u16;
typedef short bfrag __attribute__((ext_vector_type(8)));   // 8 bf16 = 4 VGPRs
typedef float f32x4 __attribute__((ext_vector_type(4)));

#define NGRAPH 512
#define BN_EPS 1e-5f

__device__ __forceinline__ float b2f(bf16 x) { return __bfloat162float(x); }
__device__ __forceinline__ float bf_lo(unsigned u) { return __uint_as_float(u << 16); }
__device__ __forceinline__ float bf_hi(unsigned u) { return __uint_as_float(u & 0xffff0000u); }
__device__ __forceinline__ u16 f2u(float v) {
    bf16 t = __float2bfloat16(v);
    u16 r; __builtin_memcpy(&r, &t, 2); return r;
}

__device__ __forceinline__ float load_f(const void* p, int i, int isbf16) {
    if (isbf16) {
        unsigned short u = ((const unsigned short*)p)[i];
        return __uint_as_float(((unsigned int)u) << 16);
    }
    return ((const float*)p)[i];
}

// ---------------- dtype detection ----------------
__global__ void detect_dtype(const void* __restrict__ x, int* __restrict__ flag) {
    int lane = threadIdx.x & 63;
    unsigned short u = ((const unsigned short*)x)[2 * lane];
    float f = __uint_as_float(((unsigned int)u) << 16);
    int crazy = (!(fabsf(f) <= 1024.0f)) ? 1 : 0;
    unsigned long long m = __ballot(crazy);
    if (threadIdx.x == 0) *flag = (m == 0ULL) ? 1 : 0;   // 1 = bf16, 0 = fp32
}

__global__ void cvt_bf(const void* __restrict__ in, u16* __restrict__ out,
                       int n, const int* __restrict__ flag) {
    int i = blockIdx.x * blockDim.x + threadIdx.x;
    if (i < n) out[i] = f2u(load_f(in, i, *flag));
}

// ---------------- repack W[K][N] into MFMA B-fragment order ----------------
__global__ void repack_w(const void* __restrict__ W, u16* __restrict__ out,
                         int Kd, int Nd, const int* __restrict__ flag) {
    int t = blockIdx.x * blockDim.x + threadIdx.x;
    if (t >= Kd * Nd) return;
    int isbf = *flag;
    int j = t & 7;
    int lane = (t >> 3) & 63;
    int tile = t >> 9;
    int NT = Nd / 16;
    int nt = tile % NT, kt = tile / NT;
    int k = kt * 32 + (lane >> 4) * 8 + j;
    int nn = nt * 16 + (lane & 15);
    out[t] = f2u(load_f(W, k * Nd + nn, isbf));
}

__global__ void fold_bn(const void* b, const void* g, const void* be,
                        const void* m, const void* v,
                        float* __restrict__ S, float* __restrict__ T,
                        int F, const int* __restrict__ flag) {
    int f = blockIdx.x * blockDim.x + threadIdx.x;
    if (f >= F) return;
    int isbf = *flag;
    float bb = load_f(b, f, isbf), gg = load_f(g, f, isbf);
    float bee = load_f(be, f, isbf), mm = load_f(m, f, isbf);
    float vv = load_f(v, f, isbf);
    float s = gg * rsqrtf(vv + BN_EPS);
    S[f] = s;
    T[f] = (bb - mm) * s + bee;
}

// ---------------- CSR build ----------------
__global__ void count_deg_i(const int* __restrict__ dst, int* __restrict__ deg, int e) {
    int i = blockIdx.x * blockDim.x + threadIdx.x;
    if (i < e) atomicAdd(&deg[dst[i]], 1);
}

__global__ void reserve_rows(const int* __restrict__ deg, int* __restrict__ row_start,
                             int* __restrict__ cursor, float* __restrict__ dis,
                             int* __restrict__ total, int n) {
    int i = blockIdx.x * blockDim.x + threadIdx.x;
    if (i >= n) return;
    int d = deg[i];
    int s = atomicAdd(total, d);
    row_start[i] = s;
    cursor[i] = s;
    dis[i] = rsqrtf((float)(d + 1));   // +1 self-loop
}

__global__ void scatter_edges(const int* __restrict__ src, const int* __restrict__ dst,
                              int* __restrict__ cursor, int* __restrict__ csr_src, int e) {
    int i = blockIdx.x * blockDim.x + threadIdx.x;
    if (i >= e) return;
    int pos = atomicAdd(&cursor[dst[i]], 1);
    csr_src[pos] = src[i];
}

// ---------------- CSR aggregation (pre-transform), bf16 in/out -------------
// LANES lanes per node (32 or 64), VPL = F/LANES features per lane.
// 4-deep load pipeline for memory-level parallelism.
template <int F, int LANES>
__global__ __launch_bounds__(256) void csr_aggf(
    const int* __restrict__ row_start, const int* __restrict__ deg,
    const float* __restrict__ dis, const int* __restrict__ csr_src,
    const u16* __restrict__ hin, u16* __restrict__ out, int n) {
    constexpr int VPL = F / LANES;       // 2 or 4
    constexpr int NPW = 64 / LANES;      // nodes per wave
    int wid = (int)(((size_t)blockIdx.x * blockDim.x + threadIdx.x) >> 6);
    int lane = threadIdx.x & 63;
    int sub = lane / LANES;
    int lanesub = lane & (LANES - 1);
    int node = wid * NPW + sub;
    if (node >= n) return;
    int start = row_start[node];
    int d = deg[node];
    float disd = dis[node];
    float dd = disd * disd;
    const int sbase = sub * LANES;

    float acc[VPL];
    {
        const u16* selfp = hin + (size_t)node * F + lanesub * VPL;
        if (VPL == 4) {
            uint2 u = *(const uint2*)selfp;
            acc[0] = bf_lo(u.x) * dd; acc[1] = bf_hi(u.x) * dd;
            acc[2] = bf_lo(u.y) * dd; acc[3] = bf_hi(u.y) * dd;
        } else {
            unsigned u = *(const unsigned*)selfp;
            acc[0] = bf_lo(u) * dd; acc[1] = bf_hi(u) * dd;
        }
    }

    for (int base = 0; base < d; base += LANES) {
        int e = base + lanesub;
        int s = 0; float nw = 0.0f;
        if (e < d) { s = csr_src[start + e]; nw = dis[s] * disd; }
        int cnt = min(LANES, d - base);
        int k = 0;
        for (; k + 4 <= cnt; k += 4) {
            int sk0 = __shfl(s, sbase + k),     sk1 = __shfl(s, sbase + k + 1);
            int sk2 = __shfl(s, sbase + k + 2), sk3 = __shfl(s, sbase + k + 3);
            float w0 = __shfl(nw, sbase + k),     w1 = __shfl(nw, sbase + k + 1);
            float w2 = __shfl(nw, sbase + k + 2), w3 = __shfl(nw, sbase + k + 3);
            if (VPL == 4) {
                uint2 a0 = *(const uint2*)(hin + (size_t)sk0 * F + lanesub * 4);
                uint2 a1 = *(const uint2*)(hin + (size_t)sk1 * F + lanesub * 4);
                uint2 a2 = *(const uint2*)(hin + (size_t)sk2 * F + lanesub * 4);
                uint2 a3 = *(const uint2*)(hin + (size_t)sk3 * F + lanesub * 4);
                acc[0] += w0 * bf_lo(a0.x); acc[1] += w0 * bf_hi(a0.x);
                acc[2] += w0 * bf_lo(a0.y); acc[3] += w0 * bf_hi(a0.y);
                acc[0] += w1 * bf_lo(a1.x); acc[1] += w1 * bf_hi(a1.x);
                acc[2] += w1 * bf_lo(a1.y); acc[3] += w1 * bf_hi(a1.y);
                acc[0] += w2 * bf_lo(a2.x); acc[1] += w2 * bf_hi(a2.x);
                acc[2] += w2 * bf_lo(a2.y); acc[3] += w2 * bf_hi(a2.y);
                acc[0] += w3 * bf_lo(a3.x); acc[1] += w3 * bf_hi(a3.x);
                acc[2] += w3 * bf_lo(a3.y); acc[3] += w3 * bf_hi(a3.y);
            } else {
                unsigned a0 = *(const unsigned*)(hin + (size_t)sk0 * F + lanesub * 2);
                unsigned a1 = *(const unsigned*)(hin + (size_t)sk1 * F + lanesub * 2);
                unsigned a2 = *(const unsigned*)(hin + (size_t)sk2 * F + lanesub * 2);
                unsigned a3 = *(const unsigned*)(hin + (size_t)sk3 * F + lanesub * 2);
                acc[0] += w0 * bf_lo(a0); acc[1] += w0 * bf_hi(a0);
                acc[0] += w1 * bf_lo(a1); acc[1] += w1 * bf_hi(a1);
                acc[0] += w2 * bf_lo(a2); acc[1] += w2 * bf_hi(a2);
                acc[0] += w3 * bf_lo(a3); acc[1] += w3 * bf_hi(a3);
            }
        }
        for (; k < cnt; k++) {
            int sk = __shfl(s, sbase + k);
            float wk = __shfl(nw, sbase + k);
            if (VPL == 4) {
                uint2 a = *(const uint2*)(hin + (size_t)sk * F + lanesub * 4);
                acc[0] += wk * bf_lo(a.x); acc[1] += wk * bf_hi(a.x);
                acc[2] += wk * bf_lo(a.y); acc[3] += wk * bf_hi(a.y);
            } else {
                unsigned a = *(const unsigned*)(hin + (size_t)sk * F + lanesub * 2);
                acc[0] += wk * bf_lo(a); acc[1] += wk * bf_hi(a);
            }
        }
    }

    u16* orow = out + (size_t)node * F + lanesub * VPL;
    if (VPL == 4) {
        uint2 o;
        o.x = (unsigned)f2u(acc[0]) | ((unsigned)f2u(acc[1]) << 16);
        o.y = (unsigned)f2u(acc[2]) | ((unsigned)f2u(acc[3]) << 16);
        *(uint2*)orow = o;
    } else {
        *(unsigned*)orow = (unsigned)f2u(acc[0]) | ((unsigned)f2u(acc[1]) << 16);
    }
}

// ---------------- MFMA GEMM + fused BN + ReLU epilogue ---------------------
// C[M x N] = relu((A[M x K] @ W[K x N]) * S + T), all bf16 in/out.
template <int K, int N>
__global__ __launch_bounds__(256) void mfma_gemm_bn(
    const u16* __restrict__ A, const u16* __restrict__ Wrep,
    const float* __restrict__ S, const float* __restrict__ T,
    u16* __restrict__ C, int M) {
    constexpr int KP = K + 8;
    constexpr int NT = N / 16;
    constexpr int KT = K / 32;
    __shared__ u16 Alds[64 * KP];
    const int m0 = blockIdx.x * 64;
    const int tid = threadIdx.x;
    for (int c = tid; c < 64 * (K / 8); c += 256) {
        int r = c / (K / 8), kc = c % (K / 8);
        uint4 v = *(const uint4*)(A + (size_t)(m0 + r) * K + kc * 8);
        *(uint4*)(&Alds[r * KP + kc * 8]) = v;
    }
    __syncthreads();
    const int wv = tid >> 6, lane = tid & 63;
    const int mrow = lane & 15;
    const int kb = lane >> 4;
    f32x4 acc[NT];
#pragma unroll
    for (int nt = 0; nt < NT; nt++) acc[nt] = (f32x4){0.f, 0.f, 0.f, 0.f};
#pragma unroll
    for (int kt = 0; kt < KT; kt++) {
        bfrag a = *(const bfrag*)(&Alds[(wv * 16 + mrow) * KP + kt * 32 + kb * 8]);
#pragma unroll
        for (int nt = 0; nt < NT; nt++) {
            bfrag b = *(const bfrag*)(Wrep + ((size_t)(kt * NT + nt) * 64 + lane) * 8);
            acc[nt] = __builtin_amdgcn_mfma_f32_16x16x32_bf16(a, b, acc[nt], 0, 0, 0);
        }
    }
#pragma unroll
    for (int nt = 0; nt < NT; nt++) {
        float s = S[nt * 16 + mrow];
        float t = T[nt * 16 + mrow];
#pragma unroll
        for (int r = 0; r < 4; r++) {
            int row = m0 + wv * 16 + kb * 4 + r;
            if (row < M)
                C[(size_t)row * N + nt * 16 + mrow] = f2u(fmaxf(acc[nt][r] * s + t, 0.0f));
        }
    }
}

// ---------------- segmented pooling over sorted batch ----------------------
#define POOL_NC 64
__global__ __launch_bounds__(256) void pool_seg(
    const u16* __restrict__ h, const int* __restrict__ batch,
    float* __restrict__ psum, float* __restrict__ pmax,
    int* __restrict__ pcnt, int n) {
    int wid = (int)(((size_t)blockIdx.x * blockDim.x + threadIdx.x) >> 6);
    int lane = threadIdx.x & 63;
    int n0 = wid * POOL_NC;
    if (n0 >= n) return;
    int n1 = min(n0 + POOL_NC, n);

    float sum[4] = {0.f, 0.f, 0.f, 0.f};
    float mx[4] = {0.f, 0.f, 0.f, 0.f};
    int cnt = 0;
    int gcur = batch[n0];

    uint2 u_next = *(const uint2*)(h + (size_t)n0 * 256 + lane * 4);
    int g_next = gcur;

    for (int node = n0; node < n1; node++) {
        uint2 u = u_next;
        int g = g_next;
        if (node + 1 < n1) {
            u_next = *(const uint2*)(h + (size_t)(node + 1) * 256 + lane * 4);
            g_next = batch[node + 1];
        }
        if (g != gcur) {
#pragma unroll
            for (int c = 0; c < 4; c++) {
                atomicAdd(&psum[gcur * 256 + lane * 4 + c], sum[c]);
                atomicMax((int*)&pmax[gcur * 256 + lane * 4 + c], __float_as_int(mx[c]));
                sum[c] = 0.f; mx[c] = 0.f;
            }
            if (lane == 0) atomicAdd(&pcnt[gcur], cnt);
            cnt = 0;
            gcur = g;
        }
        float v0 = bf_lo(u.x), v1 = bf_hi(u.x), v2 = bf_lo(u.y), v3 = bf_hi(u.y);
        sum[0] += v0; sum[1] += v1; sum[2] += v2; sum[3] += v3;
        mx[0] = fmaxf(mx[0], v0); mx[1] = fmaxf(mx[1], v1);
        mx[2] = fmaxf(mx[2], v2); mx[3] = fmaxf(mx[3], v3);
        cnt++;
    }
#pragma unroll
    for (int c = 0; c < 4; c++) {
        atomicAdd(&psum[gcur * 256 + lane * 4 + c], sum[c]);
        atomicMax((int*)&pmax[gcur * 256 + lane * 4 + c], __float_as_int(mx[c]));
    }
    if (lane == 0) atomicAdd(&pcnt[gcur], cnt);
}

__global__ void build_z(const float* __restrict__ psum, const float* __restrict__ pmax,
                        const int* __restrict__ pcnt, float* __restrict__ z) {
    int i = blockIdx.x * blockDim.x + threadIdx.x;
    if (i >= NGRAPH * 256) return;
    int g = i >> 8, f = i & 255;
    float c = (float)max(pcnt[g], 1);
    z[g * 512 + f] = psum[i] / c;
    z[g * 512 + 256 + f] = pmax[i];
}

// ---------------- MLP GEMM (block per row) ----------------
template <int K, int NOUT, bool GELU>
__global__ void mlp_gemm(const float* __restrict__ A, const void* __restrict__ W,
                         const void* __restrict__ bias, float* __restrict__ C,
                         const int* __restrict__ flag) {
    __shared__ float a[K];
    int row = blockIdx.x;
    for (int idx = threadIdx.x; idx < K; idx += blockDim.x) a[idx] = A[row * K + idx];
    __syncthreads();
    int col = threadIdx.x;
    if (col < NOUT) {
        int isbf = *flag;
        float acc = load_f(bias, col, isbf);
        if (isbf) {
            const bf16* w = (const bf16*)W;
            for (int k = 0; k < K; k++) acc += a[k] * b2f(w[k * NOUT + col]);
        } else {
            const float* w = (const float*)W;
            for (int k = 0; k < K; k++) acc += a[k] * w[k * NOUT + col];
        }
        if (GELU) acc = 0.5f * acc * (1.0f + erff(acc * 0.70710678118654752f));
        C[row * NOUT + col] = acc;
    }
}

__global__ void write_out(const float* __restrict__ in, void* __restrict__ out,
                          int n, const int* __restrict__ flag) {
    int i = blockIdx.x * blockDim.x + threadIdx.x;
    if (i >= n) return;
    if (*flag) ((bf16*)out)[i] = __float2bfloat16(in[i]);
    else       ((float*)out)[i] = in[i];
}

extern "C" void kernel_launch(void* const* d_in, const int* in_sizes, int n_in,
                              void* d_out, int out_size, void* d_ws, size_t ws_size,
                              hipStream_t stream) {
    const void* x     = d_in[0];
    const int*  ei    = (const int*)d_in[1];
    const int*  batch = (const int*)d_in[2];
    const void *W1 = d_in[3],  *b1 = d_in[4],  *g1 = d_in[5],  *be1 = d_in[6],  *m1 = d_in[7],  *v1 = d_in[8];
    const void *W2 = d_in[9],  *b2 = d_in[10], *g2 = d_in[11], *be2 = d_in[12], *m2 = d_in[13], *v2 = d_in[14];
    const void *W3 = d_in[15], *b3 = d_in[16], *g3 = d_in[17], *be3 = d_in[18], *m3 = d_in[19], *v3 = d_in[20];
    const void *Wm1 = d_in[21], *bm1 = d_in[22];
    const void *Wm2 = d_in[23], *bm2 = d_in[24];
    const void *Wm3 = d_in[25], *bm3 = d_in[26];

    const int n = in_sizes[0] / 64;     // 50000
    const int E = in_sizes[1] / 2;      // 800000
    const int* src = ei;
    const int* dst = ei + E;
    const int npad = (n + 63 + 64) & ~63;

    size_t off = 0;
    auto carve = [&](size_t bytes) {
        void* p = (char*)d_ws + off;
        off += (bytes + 255) & ~(size_t)255;
        return p;
    };
    int*   flag  = (int*)carve(4);
    int*   total = (int*)carve(4);
    float* dis   = (float*)carve((size_t)n * 4);
    int*   deg_i = (int*)carve((size_t)n * 4);
    int*   rowst = (int*)carve((size_t)n * 4);
    int*   curs  = (int*)carve((size_t)n * 4);
    int*   csrc  = (int*)carve((size_t)E * 4);
    u16*   xbf   = (u16*)carve((size_t)npad * 64 * 2);
    u16*   AG    = (u16*)carve((size_t)npad * 256 * 2);   // aggregated (pre-GEMM)
    u16*   H     = (u16*)carve((size_t)npad * 256 * 2);   // post-GEMM activations
    u16*   W1r   = (u16*)carve((size_t)64 * 128 * 2);
    u16*   W2r   = (u16*)carve((size_t)128 * 256 * 2);
    u16*   W3r   = (u16*)carve((size_t)256 * 256 * 2);
    float* S1 = (float*)carve(128 * 4); float* T1 = (float*)carve(128 * 4);
    float* S2 = (float*)carve(256 * 4); float* T2 = (float*)carve(256 * 4);
    float* S3 = (float*)carve(256 * 4); float* T3 = (float*)carve(256 * 4);
    float* psum = (float*)carve((size_t)NGRAPH * 256 * 4);
    float* pmax = (float*)carve((size_t)NGRAPH * 256 * 4);
    int*   pcnt = (int*)carve((size_t)NGRAPH * 4);
    float* z    = (float*)carve((size_t)NGRAPH * 512 * 4);
    float* z1   = (float*)carve((size_t)NGRAPH * 256 * 4);
    float* z2   = (float*)carve((size_t)NGRAPH * 128 * 4);
    float* z3   = (float*)carve((size_t)NGRAPH * 8 * 4);
    (void)ws_size; (void)n_in;

    const int BT = 256;

    detect_dtype<<<1, 64, 0, stream>>>(x, flag);
    cvt_bf<<<(n * 64 + BT - 1) / BT, BT, 0, stream>>>(x, xbf, n * 64, flag);
    repack_w<<<(64 * 128 + BT - 1) / BT, BT, 0, stream>>>(W1, W1r, 64, 128, flag);
    repack_w<<<(128 * 256 + BT - 1) / BT, BT, 0, stream>>>(W2, W2r, 128, 256, flag);
    repack_w<<<(256 * 256 + BT - 1) / BT, BT, 0, stream>>>(W3, W3r, 256, 256, flag);
    fold_bn<<<1, 128, 0, stream>>>(b1, g1, be1, m1, v1, S1, T1, 128, flag);
    fold_bn<<<1, 256, 0, stream>>>(b2, g2, be2, m2, v2, S2, T2, 256, flag);
    fold_bn<<<1, 256, 0, stream>>>(b3, g3, be3, m3, v3, S3, T3, 256, flag);

    hipMemsetAsync(deg_i, 0, (size_t)n * 4, stream);
    hipMemsetAsync(total, 0, 4, stream);
    count_deg_i<<<(E + BT - 1) / BT, BT, 0, stream>>>(dst, deg_i, E);
    reserve_rows<<<(n + BT - 1) / BT, BT, 0, stream>>>(deg_i, rowst, curs, dis, total, n);
    scatter_edges<<<(E + BT - 1) / BT, BT, 0, stream>>>(src, dst, curs, csrc, E);

    const int gblocks = (n + 63) / 64;
    // layer 1: aggregate x (64-dim, 2 nodes/wave) -> GEMM 64->128 (+BN+ReLU)
    {
        int waves = (n + 1) / 2;
        csr_aggf<64, 32><<<(waves * 64 + BT - 1) / BT, BT, 0, stream>>>(
            rowst, deg_i, dis, csrc, xbf, AG, n);
    }
    mfma_gemm_bn<64, 128><<<gblocks, 256, 0, stream>>>(AG, W1r, S1, T1, H, n);

    // layer 2: aggregate h (128-dim) -> GEMM 128->256 (+BN+ReLU)
    csr_aggf<128, 64><<<(n * 64 + BT - 1) / BT, BT, 0, stream>>>(
        rowst, deg_i, dis, csrc, H, AG, n);
    mfma_gemm_bn<128, 256><<<gblocks, 256, 0, stream>>>(AG, W2r, S2, T2, H, n);

    // layer 3: aggregate h (256-dim) -> GEMM 256->256 (+BN+ReLU)
    csr_aggf<256, 64><<<(n * 64 + BT - 1) / BT, BT, 0, stream>>>(
        rowst, deg_i, dis, csrc, H, AG, n);
    mfma_gemm_bn<256, 256><<<gblocks, 256, 0, stream>>>(AG, W3r, S3, T3, H, n);

    hipMemsetAsync(psum, 0, (size_t)NGRAPH * 256 * 4, stream);
    hipMemsetAsync(pmax, 0, (size_t)NGRAPH * 256 * 4, stream);
    hipMemsetAsync(pcnt, 0, (size_t)NGRAPH * 4, stream);
    const int pool_waves = (n + POOL_NC - 1) / POOL_NC;
    pool_seg<<<(pool_waves * 64 + BT - 1) / BT, BT, 0, stream>>>(H, batch, psum, pmax, pcnt, n);
    build_z<<<(NGRAPH * 256 + BT - 1) / BT, BT, 0, stream>>>(psum, pmax, pcnt, z);

    mlp_gemm<512, 256, true><<<NGRAPH, 256, 0, stream>>>(z, Wm1, bm1, z1, flag);
    mlp_gemm<256, 128, true><<<NGRAPH, 256, 0, stream>>>(z1, Wm2, bm2, z2, flag);
    mlp_gemm<128, 6, false><<<NGRAPH, 128, 0, stream>>>(z2, Wm3, bm3, z3, flag);
    write_out<<<(NGRAPH * 6 + BT - 1) / BT, BT, 0, stream>>>(z3, d_out, NGRAPH * 6, flag);
}